// Round 18
// baseline (147.509 us; speedup 1.0000x reference)
//
#include <hip/hip_runtime.h>
#include <stdint.h>

#define C_IN 512
#define HW 4096
#define NPIX 65536
#define KPAD 544
#define KIN 537
#define HID 512

typedef __attribute__((ext_vector_type(8))) short bf16x8;
typedef __attribute__((ext_vector_type(4))) float f32x4;

__device__ __forceinline__ unsigned short f2bf(float f) {
  union { float f; uint32_t u; } v; v.f = f;
  uint32_t u = v.u;
  return (unsigned short)((u + 0x7fffu + ((u >> 16) & 1u)) >> 16);
}
__device__ __forceinline__ float bf2f(unsigned short h) {
  union { uint32_t u; float f; } v; v.u = ((uint32_t)h) << 16;
  return v.f;
}

// ---------- merged: x fp32 [c][n] -> featB bf16 [n][c]  AND  W -> Wb ----------
__global__ __launch_bounds__(256, 8) void k_prep(const float* __restrict__ x,
                                                 unsigned short* __restrict__ featB,
                                                 const float* __restrict__ W,
                                                 unsigned short* __restrict__ Wb) {
  __shared__ unsigned short sm[64][70];
  int g = blockIdx.x;
  int t = threadIdx.x;
  if (g >= 8192) {                      // ---- W conversion tail
    int idx = (g - 8192) * 256 + t;
    if (idx < HID * KPAD) {
      int o = idx / KPAD;
      int k = idx - o * KPAD;
      float v = (k < KIN) ? W[o * KIN + k] : 0.f;
      Wb[idx] = f2bf(v);
    }
    return;
  }
  int b = g >> 9, cg = (g >> 6) & 7, pt = g & 63;
  int c0 = cg * 64, p0 = pt * 64;
  int lane = t & 63, w = t >> 6;
  const float* xb = x + ((size_t)b * C_IN + c0) * HW + p0;
#pragma unroll
  for (int i = 0; i < 8; ++i) {
    int ch = w * 16 + i * 2;
    float a = xb[(size_t)ch * HW + lane];
    float bq = xb[(size_t)(ch + 1) * HW + lane];
    uint32_t pk = (uint32_t)f2bf(a) | ((uint32_t)f2bf(bq) << 16);
    *(uint32_t*)&sm[lane][ch] = pk;   // ch even, 4B-aligned
  }
  __syncthreads();
#pragma unroll
  for (int i = 0; i < 2; ++i) {
    int px = (t >> 3) + i * 32, kg = t & 7;
    int n = b * 4096 + p0 + px;
    *(bf16x8*)(featB + (size_t)n * KPAD + c0 + kg * 8) = *(const bf16x8*)&sm[px][kg * 8];
  }
}

// ---------- MFMA correlation: band-harvest, XOR-64 LDS (8 blocks/CU) ----------
// Round-18 change vs round 17 (isolated): LDS layout back to XOR-swizzled
// [8 sr][20 sc][64 ch] (20,480 B -> 8 blocks/CU; PADC=72 was 23,040 B -> 6).
// With band-harvest the XOR key (sc&7) is di-invariant for every read site
// (B-frag sc = 4bi+i15), so all addresses precompute once and di enters as a
// +di*2560B ds_read immediate - the original XOR addressing cost is gone.
// Value-neutral slot permutation -> bit-identical output vs round 17.
__device__ __forceinline__ int xelem(int sr, int sc, int kg) {
  return (sr * 20 + sc) * 64 + ((kg ^ (sc & 7)) * 8);
}

__global__ __launch_bounds__(256, 8) void k_corr(const unsigned short* __restrict__ featB,
                                                 unsigned short* __restrict__ part) {
  __shared__ unsigned short xt[8 * 20 * 64];  // 20,480 B
  int g = blockIdx.x;
  int bid = (g & 7) * 1024 + (g >> 3);  // bijective XCD swizzle (grid = 8*1024)
  int cs = bid & 7;
  int cg = (bid >> 3) & 3;
  int rg = (bid >> 5) & 15;
  int b  = bid >> 9;
  int t = threadIdx.x;
  int lane = t & 63;
  int w = t >> 6;
  int r0 = rg * 4, c0 = cg * 16;

  // ---- stage: 1280 = 5*256 (px,kg) items from featB; 8 lanes = one px's 128B
  bf16x8 v[5];
  int la[5];
#pragma unroll
  for (int i = 0; i < 5; ++i) {
    int flat = t + i * 256;
    int kg = flat & 7, pxi = flat >> 3;
    int sc = pxi % 20, sr = pxi / 20;
    int ir = r0 - 2 + sr, ic = c0 - 2 + sc;
    la[i] = xelem(sr, sc, kg);
    if ((unsigned)ir < 64u && (unsigned)ic < 64u) {
      int n = b * 4096 + ir * 64 + ic;
      v[i] = *(const bf16x8*)(featB + (size_t)n * KPAD + cs * 64 + kg * 8);
    } else {
      v[i] = (bf16x8){0, 0, 0, 0, 0, 0, 0, 0};
    }
  }
#pragma unroll
  for (int i = 0; i < 5; ++i)
    *(bf16x8*)&xt[la[i]] = v[i];
  __syncthreads();

  int i15 = lane & 15;
  int tq = lane >> 4;

  bf16x8 afr[2];                        // A-frags: centers, reused for all 25
#pragma unroll
  for (int ks = 0; ks < 2; ++ks)
    afr[ks] = *(const bf16x8*)&xt[xelem(w + 2, 2 + i15, ks * 4 + tq)];

  // B-frag bases: di-invariant (sc = 4bi+i15); di adds +1280 elems per step
  int bBase[2][2];
#pragma unroll
  for (int bi = 0; bi < 2; ++bi)
#pragma unroll
    for (int ks = 0; ks < 2; ++ks)
      bBase[bi][ks] = xelem(w, bi * 4 + i15, ks * 4 + tq);

  // band geometry (di-independent): reg q of beta-tile bi holds pixel r=4tq+q
  // at dj' = 4bi + i15 - r; served half: bi=0 -> r<=7, bi=1 -> r>=8.
  int nb = b * 4096 + (r0 + w) * 64 + c0;
  bool take[2][4];
#pragma unroll
  for (int bi = 0; bi < 2; ++bi)
#pragma unroll
    for (int qq = 0; qq < 4; ++qq) {
      int r = 4 * tq + qq;
      int djp = bi * 4 + i15 - r;
      take[bi][qq] = (djp >= 0) && (djp <= 4) && (bi == 0 ? (r <= 7) : (r >= 8));
    }

#pragma unroll 1
  for (int di = 0; di < 5; ++di) {
    unsigned short* pb2 = part + (size_t)(cs * 5 + di) * NPIX * 5 + (size_t)5 * nb;
#pragma unroll
    for (int bi = 0; bi < 2; ++bi) {
      f32x4 acc = (f32x4){0.f, 0.f, 0.f, 0.f};
#pragma unroll
      for (int ks = 0; ks < 2; ++ks) {
        bf16x8 bfr = *(const bf16x8*)&xt[bBase[bi][ks] + di * 1280];
        acc = __builtin_amdgcn_mfma_f32_16x16x32_bf16(afr[ks], bfr, acc, 0, 0, 0);
      }
#pragma unroll
      for (int qq = 0; qq < 4; ++qq)
        if (take[bi][qq])
          pb2[4 * bi + 4 * qq + lane] = f2bf(acc[qq]);   // contiguous across lanes
    }
  }
}

// ---------- reduce partials, L2-normalize (4-lane split per pixel) ----------
__global__ __launch_bounds__(256) void k_norm(const unsigned short* __restrict__ part,
                                              unsigned short* __restrict__ featB) {
  int t = blockIdx.x * 256 + threadIdx.x;   // 1024 blocks x 256
  int n = t >> 2, csh = t & 3;
  float g[25];
#pragma unroll
  for (int k = 0; k < 25; ++k) g[k] = 0.f;
#pragma unroll
  for (int cc = 0; cc < 2; ++cc) {
    int cs = csh * 2 + cc;
#pragma unroll
    for (int di = 0; di < 5; ++di) {
      const unsigned short* pp = part + ((size_t)(cs * 5 + di) * NPIX + n) * 5;
#pragma unroll
      for (int dj = 0; dj < 5; ++dj)
        g[di * 5 + dj] += bf2f(pp[dj]);
    }
  }
#pragma unroll
  for (int k = 0; k < 25; ++k) {
    g[k] += __shfl_xor(g[k], 1);
    g[k] += __shfl_xor(g[k], 2);
  }
  float ss = 0.f;
#pragma unroll
  for (int k = 0; k < 25; ++k) ss += g[k] * g[k];
  float inv = 1.0f / sqrtf(ss + 1e-6f);
  unsigned short buf[8];
#pragma unroll
  for (int j = 0; j < 8; ++j) {
    int k = csh * 8 + j;                // csh=3 -> k 24..31 (25..31 zero-pad)
    buf[j] = (k < 25) ? f2bf(g[k] * inv) : 0;
  }
  *(bf16x8*)(featB + (size_t)n * KPAD + 512 + csh * 8) = *(bf16x8*)buf;
}

// ---------- GEMM: out(512 x 65536) = Wb(512 x 544) * featB(65536 x 544)^T ----------
typedef __attribute__((address_space(3))) unsigned int as3_uint;
typedef const __attribute__((address_space(1))) unsigned int as1_uint;

__device__ __forceinline__ void glds16(const void* g, void* l) {
  __builtin_amdgcn_global_load_lds((as1_uint*)g, (as3_uint*)l, 16, 0, 0);
}

__global__ __launch_bounds__(256) void k_gemm(const unsigned short* __restrict__ Wb,
                                              const unsigned short* __restrict__ featB,
                                              const float* __restrict__ bias,
                                              float* __restrict__ out) {
  __shared__ __attribute__((aligned(16))) unsigned short As[2][4096]; // [128 m][32 k], swz
  __shared__ __attribute__((aligned(16))) unsigned short Bs[2][4096]; // [128 n][32 k], swz
  int g = blockIdx.x;
  int bid = (g & 7) * 256 + (g >> 3);
  int mt = bid & 3;
  int nt = bid >> 2;
  int m0 = mt * 128;
  int n0 = nt * 128;
  int tid = threadIdx.x;
  int wave = tid >> 6;
  int lane = tid & 63;
  int wm = wave >> 1;
  int wn = wave & 1;
  int kg = lane >> 4;

  uint32_t aOff[4], bOff[4];
#pragma unroll
  for (int r = 0; r < 4; ++r) {
    int rr = wm * 64 + r * 16 + (lane & 15);
    aOff[r] = rr * 64 + ((kg ^ ((rr >> 1) & 3)) << 4);
  }
#pragma unroll
  for (int cb = 0; cb < 4; ++cb) {
    int rr = wn * 64 + cb * 16 + (lane & 15);
    bOff[cb] = rr * 64 + ((kg ^ ((rr >> 1) & 3)) << 4);
  }

  f32x4 acc[4][4];
#pragma unroll
  for (int r = 0; r < 4; ++r)
#pragma unroll
    for (int cb = 0; cb < 4; ++cb)
      acc[r][cb] = (f32x4){0.f, 0.f, 0.f, 0.f};

  auto STAGE = [&](int buf, int k0) {
#pragma unroll
    for (int qq = 0; qq < 2; ++qq) {
      int ci = wave * 2 + qq;
      int i = ci * 64 + lane;
      int rr = i >> 2;
      int slot = i & 3;
      int k8 = slot ^ ((rr >> 1) & 3);
      glds16(Wb + (size_t)(m0 + rr) * KPAD + k0 + k8 * 8, (char*)&As[buf][0] + ci * 1024);
      glds16(featB + (size_t)(n0 + rr) * KPAD + k0 + k8 * 8, (char*)&Bs[buf][0] + ci * 1024);
    }
  };

  STAGE(0, 0);
  __syncthreads();
  int cur = 0;
#pragma unroll 1
  for (int t = 0; t < 17; ++t) {
    if (t < 16) STAGE(cur ^ 1, (t + 1) * 32);
    const char* Ab = (const char*)&As[cur][0];
    const char* Bb = (const char*)&Bs[cur][0];
    bf16x8 af[4], bf[4];
#pragma unroll
    for (int r = 0; r < 4; ++r)
      af[r] = *(const bf16x8*)(Ab + aOff[r]);
#pragma unroll
    for (int cb = 0; cb < 4; ++cb)
      bf[cb] = *(const bf16x8*)(Bb + bOff[cb]);
#pragma unroll
    for (int cb = 0; cb < 4; ++cb)
#pragma unroll
      for (int r = 0; r < 4; ++r)
        acc[r][cb] = __builtin_amdgcn_mfma_f32_16x16x32_bf16(af[r], bf[cb], acc[r][cb], 0, 0, 0);
    __syncthreads();
    cur ^= 1;
  }

  int bb = n0 >> 12;
  int hwb = n0 & 4095;
  float* outb = out + (size_t)bb * (HID * HW) + hwb;
#pragma unroll
  for (int r = 0; r < 4; ++r) {
    int row0 = m0 + wm * 64 + r * 16 + (lane >> 4) * 4;
    float bv[4];
#pragma unroll
    for (int j = 0; j < 4; ++j) bv[j] = bias[row0 + j];
#pragma unroll
    for (int cb = 0; cb < 4; ++cb) {
      int col = wn * 64 + cb * 16 + (lane & 15);
#pragma unroll
      for (int j = 0; j < 4; ++j) {
        float v2 = acc[r][cb][j] + bv[j];
        v2 = fmaxf(v2, 0.f);
        outb[(size_t)(row0 + j) * HW + col] = v2;
      }
    }
  }
}

extern "C" void kernel_launch(void* const* d_in, const int* in_sizes, int n_in,
                              void* d_out, int out_size, void* d_ws, size_t ws_size,
                              hipStream_t stream) {
  const float* x = (const float*)d_in[0];
  const float* W = (const float*)d_in[1];
  const float* bias = (const float*)d_in[2];
  float* out = (float*)d_out;
  char* ws = (char*)d_ws;
  // ws: featB 65536x544 bf16 = 71,303,168; Wb 512x544 bf16 = 557,056;
  //     part 40 x (65536*5) bf16 = 26,214,400  (total ~98.07 MB)
  unsigned short* featB = (unsigned short*)ws;
  unsigned short* Wb = (unsigned short*)(ws + 71303168);
  unsigned short* part = (unsigned short*)(ws + 71860224);

  k_prep<<<9280, 256, 0, stream>>>(x, featB, W, Wb);
  k_corr<<<8192, 256, 0, stream>>>(featB, part);
  k_norm<<<1024, 256, 0, stream>>>(part, featB);
  k_gemm<<<2048, 256, 0, stream>>>(Wb, featB, bias, out);
}

// Round 19
// 146.396 us; speedup vs baseline: 1.0076x; 1.0076x over previous
//
#include <hip/hip_runtime.h>
#include <stdint.h>

#define C_IN 512
#define HW 4096
#define NPIX 65536
#define KPAD 544
#define KIN 537
#define HID 512

typedef __attribute__((ext_vector_type(8))) short bf16x8;
typedef __attribute__((ext_vector_type(4))) float f32x4;

__device__ __forceinline__ unsigned short f2bf(float f) {
  union { float f; uint32_t u; } v; v.f = f;
  uint32_t u = v.u;
  return (unsigned short)((u + 0x7fffu + ((u >> 16) & 1u)) >> 16);
}
__device__ __forceinline__ float bf2f(unsigned short h) {
  union { uint32_t u; float f; } v; v.u = ((uint32_t)h) << 16;
  return v.f;
}

// ---------- merged: x fp32 [c][n] -> featB bf16 [n][c]  AND  W -> Wb ----------
__global__ __launch_bounds__(256, 8) void k_prep(const float* __restrict__ x,
                                                 unsigned short* __restrict__ featB,
                                                 const float* __restrict__ W,
                                                 unsigned short* __restrict__ Wb) {
  __shared__ unsigned short sm[64][70];
  int g = blockIdx.x;
  int t = threadIdx.x;
  if (g >= 8192) {                      // ---- W conversion tail
    int idx = (g - 8192) * 256 + t;
    if (idx < HID * KPAD) {
      int o = idx / KPAD;
      int k = idx - o * KPAD;
      float v = (k < KIN) ? W[o * KIN + k] : 0.f;
      Wb[idx] = f2bf(v);
    }
    return;
  }
  int b = g >> 9, cg = (g >> 6) & 7, pt = g & 63;
  int c0 = cg * 64, p0 = pt * 64;
  int lane = t & 63, w = t >> 6;
  const float* xb = x + ((size_t)b * C_IN + c0) * HW + p0;
#pragma unroll
  for (int i = 0; i < 8; ++i) {
    int ch = w * 16 + i * 2;
    float a = xb[(size_t)ch * HW + lane];
    float bq = xb[(size_t)(ch + 1) * HW + lane];
    uint32_t pk = (uint32_t)f2bf(a) | ((uint32_t)f2bf(bq) << 16);
    *(uint32_t*)&sm[lane][ch] = pk;   // ch even, 4B-aligned
  }
  __syncthreads();
#pragma unroll
  for (int i = 0; i < 2; ++i) {
    int px = (t >> 3) + i * 32, kg = t & 7;
    int n = b * 4096 + p0 + px;
    *(bf16x8*)(featB + (size_t)n * KPAD + c0 + kg * 8) = *(const bf16x8*)&sm[px][kg * 8];
  }
}

// ---------- MFMA correlation: band-harvest, XOR-64 LDS (round 18) ----------
__device__ __forceinline__ int xelem(int sr, int sc, int kg) {
  return (sr * 20 + sc) * 64 + ((kg ^ (sc & 7)) * 8);
}

__global__ __launch_bounds__(256, 8) void k_corr(const unsigned short* __restrict__ featB,
                                                 unsigned short* __restrict__ part) {
  __shared__ unsigned short xt[8 * 20 * 64];  // 20,480 B
  int g = blockIdx.x;
  int bid = (g & 7) * 1024 + (g >> 3);  // bijective XCD swizzle (grid = 8*1024)
  int cs = bid & 7;
  int cg = (bid >> 3) & 3;
  int rg = (bid >> 5) & 15;
  int b  = bid >> 9;
  int t = threadIdx.x;
  int lane = t & 63;
  int w = t >> 6;
  int r0 = rg * 4, c0 = cg * 16;

  // ---- stage: 1280 = 5*256 (px,kg) items from featB; 8 lanes = one px's 128B
  bf16x8 v[5];
  int la[5];
#pragma unroll
  for (int i = 0; i < 5; ++i) {
    int flat = t + i * 256;
    int kg = flat & 7, pxi = flat >> 3;
    int sc = pxi % 20, sr = pxi / 20;
    int ir = r0 - 2 + sr, ic = c0 - 2 + sc;
    la[i] = xelem(sr, sc, kg);
    if ((unsigned)ir < 64u && (unsigned)ic < 64u) {
      int n = b * 4096 + ir * 64 + ic;
      v[i] = *(const bf16x8*)(featB + (size_t)n * KPAD + cs * 64 + kg * 8);
    } else {
      v[i] = (bf16x8){0, 0, 0, 0, 0, 0, 0, 0};
    }
  }
#pragma unroll
  for (int i = 0; i < 5; ++i)
    *(bf16x8*)&xt[la[i]] = v[i];
  __syncthreads();

  int i15 = lane & 15;
  int tq = lane >> 4;

  bf16x8 afr[2];                        // A-frags: centers, reused for all 25
#pragma unroll
  for (int ks = 0; ks < 2; ++ks)
    afr[ks] = *(const bf16x8*)&xt[xelem(w + 2, 2 + i15, ks * 4 + tq)];

  // B-frag bases: di-invariant (sc = 4bi+i15); di adds +1280 elems per step
  int bBase[2][2];
#pragma unroll
  for (int bi = 0; bi < 2; ++bi)
#pragma unroll
    for (int ks = 0; ks < 2; ++ks)
      bBase[bi][ks] = xelem(w, bi * 4 + i15, ks * 4 + tq);

  // band geometry (di-independent): reg q of beta-tile bi holds pixel r=4tq+q
  // at dj' = 4bi + i15 - r; served half: bi=0 -> r<=7, bi=1 -> r>=8.
  int nb = b * 4096 + (r0 + w) * 64 + c0;
  bool take[2][4];
#pragma unroll
  for (int bi = 0; bi < 2; ++bi)
#pragma unroll
    for (int qq = 0; qq < 4; ++qq) {
      int r = 4 * tq + qq;
      int djp = bi * 4 + i15 - r;
      take[bi][qq] = (djp >= 0) && (djp <= 4) && (bi == 0 ? (r <= 7) : (r >= 8));
    }

#pragma unroll 1
  for (int di = 0; di < 5; ++di) {
    unsigned short* pb2 = part + (size_t)(cs * 5 + di) * NPIX * 5 + (size_t)5 * nb;
#pragma unroll
    for (int bi = 0; bi < 2; ++bi) {
      f32x4 acc = (f32x4){0.f, 0.f, 0.f, 0.f};
#pragma unroll
      for (int ks = 0; ks < 2; ++ks) {
        bf16x8 bfr = *(const bf16x8*)&xt[bBase[bi][ks] + di * 1280];
        acc = __builtin_amdgcn_mfma_f32_16x16x32_bf16(afr[ks], bfr, acc, 0, 0, 0);
      }
#pragma unroll
      for (int qq = 0; qq < 4; ++qq)
        if (take[bi][qq])
          pb2[4 * bi + 4 * qq + lane] = f2bf(acc[qq]);   // contiguous across lanes
    }
  }
}

// ---------- reduce partials, L2-normalize (4-lane split per pixel) ----------
__global__ __launch_bounds__(256) void k_norm(const unsigned short* __restrict__ part,
                                              unsigned short* __restrict__ featB) {
  int t = blockIdx.x * 256 + threadIdx.x;   // 1024 blocks x 256
  int n = t >> 2, csh = t & 3;
  float g[25];
#pragma unroll
  for (int k = 0; k < 25; ++k) g[k] = 0.f;
#pragma unroll
  for (int cc = 0; cc < 2; ++cc) {
    int cs = csh * 2 + cc;
#pragma unroll
    for (int di = 0; di < 5; ++di) {
      const unsigned short* pp = part + ((size_t)(cs * 5 + di) * NPIX + n) * 5;
#pragma unroll
      for (int dj = 0; dj < 5; ++dj)
        g[di * 5 + dj] += bf2f(pp[dj]);
    }
  }
#pragma unroll
  for (int k = 0; k < 25; ++k) {
    g[k] += __shfl_xor(g[k], 1);
    g[k] += __shfl_xor(g[k], 2);
  }
  float ss = 0.f;
#pragma unroll
  for (int k = 0; k < 25; ++k) ss += g[k] * g[k];
  float inv = 1.0f / sqrtf(ss + 1e-6f);
  unsigned short buf[8];
#pragma unroll
  for (int j = 0; j < 8; ++j) {
    int k = csh * 8 + j;                // csh=3 -> k 24..31 (25..31 zero-pad)
    buf[j] = (k < 25) ? f2bf(g[k] * inv) : 0;
  }
  *(bf16x8*)(featB + (size_t)n * KPAD + 512 + csh * 8) = *(bf16x8*)buf;
}

// ---------- GEMM: out(512 x 65536) = Wb(512 x 544) * featB(65536 x 544)^T ----------
// Round-19 change (isolated): counted-vmcnt pipeline (T4). Raw s_barrier (no
// compiler vmcnt(0) drain) + s_waitcnt vmcnt(4): tile t+1's 4 global_load_lds
// stay in flight across the barrier while tile t computes. STAGE for t+2 is
// issued after barrier-2 (all waves done reading buf[cur]) -> race-free.
// Ledger: 8 loads in flight at each wait; vmcnt(4) retires exactly tile t.
typedef __attribute__((address_space(3))) unsigned int as3_uint;
typedef const __attribute__((address_space(1))) unsigned int as1_uint;

__device__ __forceinline__ void glds16(const void* g, void* l) {
  __builtin_amdgcn_global_load_lds((as1_uint*)g, (as3_uint*)l, 16, 0, 0);
}

__global__ __launch_bounds__(256) void k_gemm(const unsigned short* __restrict__ Wb,
                                              const unsigned short* __restrict__ featB,
                                              const float* __restrict__ bias,
                                              float* __restrict__ out) {
  __shared__ __attribute__((aligned(16))) unsigned short As[2][4096]; // [128 m][32 k], swz
  __shared__ __attribute__((aligned(16))) unsigned short Bs[2][4096]; // [128 n][32 k], swz
  int g = blockIdx.x;
  int bid = (g & 7) * 256 + (g >> 3);
  int mt = bid & 3;
  int nt = bid >> 2;
  int m0 = mt * 128;
  int n0 = nt * 128;
  int tid = threadIdx.x;
  int wave = tid >> 6;
  int lane = tid & 63;
  int wm = wave >> 1;
  int wn = wave & 1;
  int kg = lane >> 4;

  uint32_t aOff[4], bOff[4];
#pragma unroll
  for (int r = 0; r < 4; ++r) {
    int rr = wm * 64 + r * 16 + (lane & 15);
    aOff[r] = rr * 64 + ((kg ^ ((rr >> 1) & 3)) << 4);
  }
#pragma unroll
  for (int cb = 0; cb < 4; ++cb) {
    int rr = wn * 64 + cb * 16 + (lane & 15);
    bOff[cb] = rr * 64 + ((kg ^ ((rr >> 1) & 3)) << 4);
  }

  f32x4 acc[4][4];
#pragma unroll
  for (int r = 0; r < 4; ++r)
#pragma unroll
    for (int cb = 0; cb < 4; ++cb)
      acc[r][cb] = (f32x4){0.f, 0.f, 0.f, 0.f};

  auto STAGE = [&](int buf, int k0) {
#pragma unroll
    for (int qq = 0; qq < 2; ++qq) {
      int ci = wave * 2 + qq;
      int i = ci * 64 + lane;
      int rr = i >> 2;
      int slot = i & 3;
      int k8 = slot ^ ((rr >> 1) & 3);
      glds16(Wb + (size_t)(m0 + rr) * KPAD + k0 + k8 * 8, (char*)&As[buf][0] + ci * 1024);
      glds16(featB + (size_t)(n0 + rr) * KPAD + k0 + k8 * 8, (char*)&Bs[buf][0] + ci * 1024);
    }
  };

  STAGE(0, 0);
  STAGE(1, 32);
  int cur = 0;
#pragma unroll 1
  for (int t = 0; t < 17; ++t) {
    if (t < 16)
      asm volatile("s_waitcnt vmcnt(4)" ::: "memory");  // tile t landed; t+1 in flight
    else
      asm volatile("s_waitcnt vmcnt(0)" ::: "memory");  // tail drain
    __builtin_amdgcn_s_barrier();                        // raw: no vmcnt drain
    const char* Ab = (const char*)&As[cur][0];
    const char* Bb = (const char*)&Bs[cur][0];
    bf16x8 af[4], bf[4];
#pragma unroll
    for (int r = 0; r < 4; ++r)
      af[r] = *(const bf16x8*)(Ab + aOff[r]);
#pragma unroll
    for (int cb = 0; cb < 4; ++cb)
      bf[cb] = *(const bf16x8*)(Bb + bOff[cb]);
#pragma unroll
    for (int cb = 0; cb < 4; ++cb)
#pragma unroll
      for (int r = 0; r < 4; ++r)
        acc[r][cb] = __builtin_amdgcn_mfma_f32_16x16x32_bf16(af[r], bf[cb], acc[r][cb], 0, 0, 0);
    __builtin_amdgcn_s_barrier();                        // all waves done reading buf[cur]
    if (t < 15) STAGE(cur, (t + 2) * 32);                // overwrite consumed buffer
    cur ^= 1;
  }

  int bb = n0 >> 12;
  int hwb = n0 & 4095;
  float* outb = out + (size_t)bb * (HID * HW) + hwb;
#pragma unroll
  for (int r = 0; r < 4; ++r) {
    int row0 = m0 + wm * 64 + r * 16 + (lane >> 4) * 4;
    float bv[4];
#pragma unroll
    for (int j = 0; j < 4; ++j) bv[j] = bias[row0 + j];
#pragma unroll
    for (int cb = 0; cb < 4; ++cb) {
      int col = wn * 64 + cb * 16 + (lane & 15);
#pragma unroll
      for (int j = 0; j < 4; ++j) {
        float v2 = acc[r][cb][j] + bv[j];
        v2 = fmaxf(v2, 0.f);
        outb[(size_t)(row0 + j) * HW + col] = v2;
      }
    }
  }
}

extern "C" void kernel_launch(void* const* d_in, const int* in_sizes, int n_in,
                              void* d_out, int out_size, void* d_ws, size_t ws_size,
                              hipStream_t stream) {
  const float* x = (const float*)d_in[0];
  const float* W = (const float*)d_in[1];
  const float* bias = (const float*)d_in[2];
  float* out = (float*)d_out;
  char* ws = (char*)d_ws;
  // ws: featB 65536x544 bf16 = 71,303,168; Wb 512x544 bf16 = 557,056;
  //     part 40 x (65536*5) bf16 = 26,214,400  (total ~98.07 MB)
  unsigned short* featB = (unsigned short*)ws;
  unsigned short* Wb = (unsigned short*)(ws + 71303168);
  unsigned short* part = (unsigned short*)(ws + 71860224);

  k_prep<<<9280, 256, 0, stream>>>(x, featB, W, Wb);
  k_corr<<<8192, 256, 0, stream>>>(featB, part);
  k_norm<<<1024, 256, 0, stream>>>(part, featB);
  k_gemm<<<2048, 256, 0, stream>>>(Wb, featB, bias, out);
}

// Round 20
// 140.473 us; speedup vs baseline: 1.0501x; 1.0422x over previous
//
#include <hip/hip_runtime.h>
#include <stdint.h>

#define C_IN 512
#define HW 4096
#define NPIX 65536
#define KPAD 576
#define KIN 537
#define HID 512

typedef __attribute__((ext_vector_type(8))) short bf16x8;
typedef __attribute__((ext_vector_type(4))) float f32x4;

__device__ __forceinline__ unsigned short f2bf(float f) {
  union { float f; uint32_t u; } v; v.f = f;
  uint32_t u = v.u;
  return (unsigned short)((u + 0x7fffu + ((u >> 16) & 1u)) >> 16);
}
__device__ __forceinline__ float bf2f(unsigned short h) {
  union { uint32_t u; float f; } v; v.u = ((uint32_t)h) << 16;
  return v.f;
}

// ---------- merged: x fp32 [c][n] -> featB bf16 [n][c]  AND  W -> Wb ----------
__global__ __launch_bounds__(256, 8) void k_prep(const float* __restrict__ x,
                                                 unsigned short* __restrict__ featB,
                                                 const float* __restrict__ W,
                                                 unsigned short* __restrict__ Wb) {
  __shared__ unsigned short sm[64][70];
  int g = blockIdx.x;
  int t = threadIdx.x;
  if (g >= 8192) {                      // ---- W conversion tail (512 x 576, zero-pad)
    int idx = (g - 8192) * 256 + t;
    if (idx < HID * KPAD) {
      int o = idx / KPAD;
      int k = idx - o * KPAD;
      float v = (k < KIN) ? W[o * KIN + k] : 0.f;
      Wb[idx] = f2bf(v);
    }
    return;
  }
  int b = g >> 9, cg = (g >> 6) & 7, pt = g & 63;
  int c0 = cg * 64, p0 = pt * 64;
  int lane = t & 63, w = t >> 6;
  const float* xb = x + ((size_t)b * C_IN + c0) * HW + p0;
#pragma unroll
  for (int i = 0; i < 8; ++i) {
    int ch = w * 16 + i * 2;
    float a = xb[(size_t)ch * HW + lane];
    float bq = xb[(size_t)(ch + 1) * HW + lane];
    uint32_t pk = (uint32_t)f2bf(a) | ((uint32_t)f2bf(bq) << 16);
    *(uint32_t*)&sm[lane][ch] = pk;   // ch even, 4B-aligned
  }
  __syncthreads();
#pragma unroll
  for (int i = 0; i < 2; ++i) {
    int px = (t >> 3) + i * 32, kg = t & 7;
    int n = b * 4096 + p0 + px;
    *(bf16x8*)(featB + (size_t)n * KPAD + c0 + kg * 8) = *(const bf16x8*)&sm[px][kg * 8];
  }
}

// ---------- MFMA correlation: band-harvest, XOR-64 LDS (round 18, stride 576) ----------
__device__ __forceinline__ int xelem(int sr, int sc, int kg) {
  return (sr * 20 + sc) * 64 + ((kg ^ (sc & 7)) * 8);
}

__global__ __launch_bounds__(256, 8) void k_corr(const unsigned short* __restrict__ featB,
                                                 unsigned short* __restrict__ part) {
  __shared__ unsigned short xt[8 * 20 * 64];  // 20,480 B
  int g = blockIdx.x;
  int bid = (g & 7) * 1024 + (g >> 3);  // bijective XCD swizzle (grid = 8*1024)
  int cs = bid & 7;
  int cg = (bid >> 3) & 3;
  int rg = (bid >> 5) & 15;
  int b  = bid >> 9;
  int t = threadIdx.x;
  int lane = t & 63;
  int w = t >> 6;
  int r0 = rg * 4, c0 = cg * 16;

  bf16x8 v[5];
  int la[5];
#pragma unroll
  for (int i = 0; i < 5; ++i) {
    int flat = t + i * 256;
    int kg = flat & 7, pxi = flat >> 3;
    int sc = pxi % 20, sr = pxi / 20;
    int ir = r0 - 2 + sr, ic = c0 - 2 + sc;
    la[i] = xelem(sr, sc, kg);
    if ((unsigned)ir < 64u && (unsigned)ic < 64u) {
      int n = b * 4096 + ir * 64 + ic;
      v[i] = *(const bf16x8*)(featB + (size_t)n * KPAD + cs * 64 + kg * 8);
    } else {
      v[i] = (bf16x8){0, 0, 0, 0, 0, 0, 0, 0};
    }
  }
#pragma unroll
  for (int i = 0; i < 5; ++i)
    *(bf16x8*)&xt[la[i]] = v[i];
  __syncthreads();

  int i15 = lane & 15;
  int tq = lane >> 4;

  bf16x8 afr[2];
#pragma unroll
  for (int ks = 0; ks < 2; ++ks)
    afr[ks] = *(const bf16x8*)&xt[xelem(w + 2, 2 + i15, ks * 4 + tq)];

  int bBase[2][2];
#pragma unroll
  for (int bi = 0; bi < 2; ++bi)
#pragma unroll
    for (int ks = 0; ks < 2; ++ks)
      bBase[bi][ks] = xelem(w, bi * 4 + i15, ks * 4 + tq);

  int nb = b * 4096 + (r0 + w) * 64 + c0;
  bool take[2][4];
#pragma unroll
  for (int bi = 0; bi < 2; ++bi)
#pragma unroll
    for (int qq = 0; qq < 4; ++qq) {
      int r = 4 * tq + qq;
      int djp = bi * 4 + i15 - r;
      take[bi][qq] = (djp >= 0) && (djp <= 4) && (bi == 0 ? (r <= 7) : (r >= 8));
    }

#pragma unroll 1
  for (int di = 0; di < 5; ++di) {
    unsigned short* pb2 = part + (size_t)(cs * 5 + di) * NPIX * 5 + (size_t)5 * nb;
#pragma unroll
    for (int bi = 0; bi < 2; ++bi) {
      f32x4 acc = (f32x4){0.f, 0.f, 0.f, 0.f};
#pragma unroll
      for (int ks = 0; ks < 2; ++ks) {
        bf16x8 bfr = *(const bf16x8*)&xt[bBase[bi][ks] + di * 1280];
        acc = __builtin_amdgcn_mfma_f32_16x16x32_bf16(afr[ks], bfr, acc, 0, 0, 0);
      }
#pragma unroll
      for (int qq = 0; qq < 4; ++qq)
        if (take[bi][qq])
          pb2[4 * bi + 4 * qq + lane] = f2bf(acc[qq]);
    }
  }
}

// ---------- reduce partials, L2-normalize (4-lane split); zero-fill k 544..575 ----------
__global__ __launch_bounds__(256) void k_norm(const unsigned short* __restrict__ part,
                                              unsigned short* __restrict__ featB) {
  int t = blockIdx.x * 256 + threadIdx.x;   // 1024 blocks x 256
  int n = t >> 2, csh = t & 3;
  float g[25];
#pragma unroll
  for (int k = 0; k < 25; ++k) g[k] = 0.f;
#pragma unroll
  for (int cc = 0; cc < 2; ++cc) {
    int cs = csh * 2 + cc;
#pragma unroll
    for (int di = 0; di < 5; ++di) {
      const unsigned short* pp = part + ((size_t)(cs * 5 + di) * NPIX + n) * 5;
#pragma unroll
      for (int dj = 0; dj < 5; ++dj)
        g[di * 5 + dj] += bf2f(pp[dj]);
    }
  }
#pragma unroll
  for (int k = 0; k < 25; ++k) {
    g[k] += __shfl_xor(g[k], 1);
    g[k] += __shfl_xor(g[k], 2);
  }
  float ss = 0.f;
#pragma unroll
  for (int k = 0; k < 25; ++k) ss += g[k] * g[k];
  float inv = 1.0f / sqrtf(ss + 1e-6f);
  unsigned short buf[16];
#pragma unroll
  for (int j = 0; j < 16; ++j) {
    int k = csh * 16 + j;               // csh covers 512..575 (16 each)
    buf[j] = (k < 25) ? f2bf(g[k] * inv) : 0;
  }
  unsigned short* fb = featB + (size_t)n * KPAD + 512 + csh * 16;
  *(bf16x8*)(fb) = *(bf16x8*)&buf[0];
  *(bf16x8*)(fb + 8) = *(bf16x8*)&buf[8];
}

// ---------- GEMM: 256x256 tile, BK=64, 8 waves, st_16x32 swizzle, 2-deep vmcnt ----------
// Round-20: r19's verified sync skeleton (raw s_barrier + counted vmcnt, 2-deep
// prefetch) scaled to the m201 geometry. Per K-tile per wave: 64 MFMA, 32
// ds_read_b128, 8 global_load_lds; 2 barriers -> 4x amortization vs r19.
// Swizzle (rule #21, both sides): LDS dest linear (slot*16), global source at
// inverse-swizzled (row,col); ds_read applies byte ^ (((byte>>9)&1)<<5)
// (st_16x32). vmcnt ledger: 8 loads/tile/thread; entry vmcnt(8) = tile t
// landed, tile t+1 in flight across the barrier; tail drains vmcnt(0).
typedef __attribute__((address_space(3))) unsigned int as3_uint;
typedef const __attribute__((address_space(1))) unsigned int as1_uint;

__device__ __forceinline__ void glds16(const void* g, void* l) {
  __builtin_amdgcn_global_load_lds((as1_uint*)g, (as3_uint*)l, 16, 0, 0);
}

__global__ __launch_bounds__(512, 2) void k_gemm(const unsigned short* __restrict__ Wb,
                                                 const unsigned short* __restrict__ featB,
                                                 const float* __restrict__ bias,
                                                 float* __restrict__ out) {
  __shared__ __attribute__((aligned(16))) unsigned short As[2][16384]; // 2 x 32 KB
  __shared__ __attribute__((aligned(16))) unsigned short Bs[2][16384]; // 2 x 32 KB
  int g = blockIdx.x;
  int bid = (g & 7) * 64 + (g >> 3);    // XCD swizzle (512 = 8*64); mt-pair adjacent
  int mt = bid & 1;
  int nt = bid >> 1;
  int m0 = mt * 256;
  int n0 = nt * 256;
  int tid = threadIdx.x;
  int wave = tid >> 6;                  // 0..7 = 2m x 4n
  int lane = tid & 63;
  int wm = wave >> 2;                   // 0..1 -> rows wm*128..+128
  int wn = wave & 3;                    // 0..3 -> cols wn*64..+64

  // staging source coords from linear LDS slot (inverse st_16x32)
  int srow[4], scol[4];
#pragma unroll
  for (int i = 0; i < 4; ++i) {
    uint32_t L = (uint32_t)(i * 512 + tid) * 16;
    uint32_t Lp = L ^ (((L >> 9) & 1) << 5);
    srow[i] = Lp >> 7;                  // 0..255
    scol[i] = (Lp >> 4) & 7;            // 16B chunk within 128B row
  }

  auto STAGE = [&](int buf, int k0) {
#pragma unroll
    for (int i = 0; i < 4; ++i) {
      char* la = (char*)&As[buf][0] + i * 8192 + wave * 1024;
      char* lb = (char*)&Bs[buf][0] + i * 8192 + wave * 1024;
      glds16(Wb + (size_t)(m0 + srow[i]) * KPAD + k0 + scol[i] * 8, la);
      glds16(featB + (size_t)(n0 + srow[i]) * KPAD + k0 + scol[i] * 8, lb);
    }
  };

  int laneRow = lane & 15;
  int kswz[2];
#pragma unroll
  for (int ks = 0; ks < 2; ++ks)
    kswz[ks] = (ks * 64 + (lane >> 4) * 16) ^ ((lane & 4) << 3);

  f32x4 acc[8][4];
#pragma unroll
  for (int r = 0; r < 8; ++r)
#pragma unroll
    for (int c = 0; c < 4; ++c)
      acc[r][c] = (f32x4){0.f, 0.f, 0.f, 0.f};

  STAGE(0, 0);
  STAGE(1, 64);
  const int NT = 9;                     // K = 576 = 9 x 64
#pragma unroll 1
  for (int t = 0; t < NT; ++t) {
    if (t < NT - 1)
      asm volatile("s_waitcnt vmcnt(8)" ::: "memory");  // tile t landed; t+1 in flight
    else
      asm volatile("s_waitcnt vmcnt(0)" ::: "memory");  // tail drain
    __builtin_amdgcn_s_barrier();
    const char* Ab = (const char*)&As[t & 1][0];
    const char* Bb = (const char*)&Bs[t & 1][0];
#pragma unroll
    for (int mh = 0; mh < 2; ++mh) {
      bf16x8 af[4][2];
#pragma unroll
      for (int f = 0; f < 4; ++f)
#pragma unroll
        for (int ks = 0; ks < 2; ++ks)
          af[f][ks] = *(const bf16x8*)(Ab +
              (wm * 128 + mh * 64 + f * 16 + laneRow) * 128 + kswz[ks]);
#pragma unroll
      for (int nh = 0; nh < 2; ++nh) {
        bf16x8 bf[2][2];
#pragma unroll
        for (int nf = 0; nf < 2; ++nf)
#pragma unroll
          for (int ks = 0; ks < 2; ++ks)
            bf[nf][ks] = *(const bf16x8*)(Bb +
                (wn * 64 + nh * 32 + nf * 16 + laneRow) * 128 + kswz[ks]);
        __builtin_amdgcn_s_setprio(1);
#pragma unroll
        for (int f = 0; f < 4; ++f)
#pragma unroll
          for (int nf = 0; nf < 2; ++nf)
#pragma unroll
            for (int ks = 0; ks < 2; ++ks)
              acc[mh * 4 + f][nh * 2 + nf] = __builtin_amdgcn_mfma_f32_16x16x32_bf16(
                  af[f][ks], bf[nf][ks], acc[mh * 4 + f][nh * 2 + nf], 0, 0, 0);
        __builtin_amdgcn_s_setprio(0);
      }
    }
    __builtin_amdgcn_s_barrier();       // all reads of buf[t&1] done
    if (t + 2 < NT) STAGE(t & 1, (t + 2) * 64);
  }

  int bb = n0 >> 12;
  int hwb = n0 & 4095;
  float* outb = out + (size_t)bb * (HID * HW) + hwb;
#pragma unroll
  for (int f8 = 0; f8 < 8; ++f8) {
    int row0 = m0 + wm * 128 + f8 * 16 + (lane >> 4) * 4;
    float bv[4];
#pragma unroll
    for (int j = 0; j < 4; ++j) bv[j] = bias[row0 + j];
#pragma unroll
    for (int c = 0; c < 4; ++c) {
      int col = wn * 64 + (c >> 1) * 32 + (c & 1) * 16 + (lane & 15);
#pragma unroll
      for (int j = 0; j < 4; ++j) {
        float v2 = acc[f8][c][j] + bv[j];
        v2 = fmaxf(v2, 0.f);
        outb[(size_t)(row0 + j) * HW + col] = v2;
      }
    }
  }
}

extern "C" void kernel_launch(void* const* d_in, const int* in_sizes, int n_in,
                              void* d_out, int out_size, void* d_ws, size_t ws_size,
                              hipStream_t stream) {
  const float* x = (const float*)d_in[0];
  const float* W = (const float*)d_in[1];
  const float* bias = (const float*)d_in[2];
  float* out = (float*)d_out;
  char* ws = (char*)d_ws;
  // ws: featB 65536x576 bf16 = 75,497,472; Wb 512x576 bf16 = 589,824;
  //     part 40 x (65536*5) bf16 = 26,214,400  (total ~102.3 MB; round-6
  //     evidence shows ws_size >= 124 MB)
  unsigned short* featB = (unsigned short*)ws;
  unsigned short* Wb = (unsigned short*)(ws + 75497472);
  unsigned short* part = (unsigned short*)(ws + 76087296);

  k_prep<<<9344, 256, 0, stream>>>(x, featB, W, Wb);
  k_corr<<<8192, 256, 0, stream>>>(featB, part);
  k_norm<<<1024, 256, 0, stream>>>(part, featB);
  k_gemm<<<512, 512, 0, stream>>>(Wb, featB, bias, out);
}

// Round 21
// 138.756 us; speedup vs baseline: 1.0631x; 1.0124x over previous
//
#include <hip/hip_runtime.h>
#include <hip/hip_bf16.h>
#include <stdint.h>

#define C_IN 512
#define HW 4096
#define NPIX 65536
#define KPAD 576
#define KIN 537
#define HID 512

typedef __attribute__((ext_vector_type(8))) short bf16x8;
typedef __attribute__((ext_vector_type(4))) float f32x4;

// Round-21 change (isolated): native RTNE cast (compiler v_cvt lowering,
// ~1-2 ops) replaces the 5-op manual round-to-nearest-even. Bit-identical
// values (both RTNE). k_corr: 40 casts/thread (~45% of its VALU ops).
__device__ __forceinline__ unsigned short f2bf(float f) {
  union { __hip_bfloat16 h; unsigned short u; } v;
  v.h = __float2bfloat16(f);
  return v.u;
}
__device__ __forceinline__ float bf2f(unsigned short h) {
  union { uint32_t u; float f; } v; v.u = ((uint32_t)h) << 16;
  return v.f;
}

// ---------- merged: x fp32 [c][n] -> featB bf16 [n][c]  AND  W -> Wb ----------
__global__ __launch_bounds__(256, 8) void k_prep(const float* __restrict__ x,
                                                 unsigned short* __restrict__ featB,
                                                 const float* __restrict__ W,
                                                 unsigned short* __restrict__ Wb) {
  __shared__ unsigned short sm[64][70];
  int g = blockIdx.x;
  int t = threadIdx.x;
  if (g >= 8192) {                      // ---- W conversion tail (512 x 576, zero-pad)
    int idx = (g - 8192) * 256 + t;
    if (idx < HID * KPAD) {
      int o = idx / KPAD;
      int k = idx - o * KPAD;
      float v = (k < KIN) ? W[o * KIN + k] : 0.f;
      Wb[idx] = f2bf(v);
    }
    return;
  }
  int b = g >> 9, cg = (g >> 6) & 7, pt = g & 63;
  int c0 = cg * 64, p0 = pt * 64;
  int lane = t & 63, w = t >> 6;
  const float* xb = x + ((size_t)b * C_IN + c0) * HW + p0;
#pragma unroll
  for (int i = 0; i < 8; ++i) {
    int ch = w * 16 + i * 2;
    float a = xb[(size_t)ch * HW + lane];
    float bq = xb[(size_t)(ch + 1) * HW + lane];
    uint32_t pk = (uint32_t)f2bf(a) | ((uint32_t)f2bf(bq) << 16);
    *(uint32_t*)&sm[lane][ch] = pk;   // ch even, 4B-aligned
  }
  __syncthreads();
#pragma unroll
  for (int i = 0; i < 2; ++i) {
    int px = (t >> 3) + i * 32, kg = t & 7;
    int n = b * 4096 + p0 + px;
    *(bf16x8*)(featB + (size_t)n * KPAD + c0 + kg * 8) = *(const bf16x8*)&sm[px][kg * 8];
  }
}

// ---------- MFMA correlation: band-harvest, XOR-64 LDS (round 18, stride 576) ----------
__device__ __forceinline__ int xelem(int sr, int sc, int kg) {
  return (sr * 20 + sc) * 64 + ((kg ^ (sc & 7)) * 8);
}

__global__ __launch_bounds__(256, 8) void k_corr(const unsigned short* __restrict__ featB,
                                                 unsigned short* __restrict__ part) {
  __shared__ unsigned short xt[8 * 20 * 64];  // 20,480 B
  int g = blockIdx.x;
  int bid = (g & 7) * 1024 + (g >> 3);  // bijective XCD swizzle (grid = 8*1024)
  int cs = bid & 7;
  int cg = (bid >> 3) & 3;
  int rg = (bid >> 5) & 15;
  int b  = bid >> 9;
  int t = threadIdx.x;
  int lane = t & 63;
  int w = t >> 6;
  int r0 = rg * 4, c0 = cg * 16;

  bf16x8 v[5];
  int la[5];
#pragma unroll
  for (int i = 0; i < 5; ++i) {
    int flat = t + i * 256;
    int kg = flat & 7, pxi = flat >> 3;
    int sc = pxi % 20, sr = pxi / 20;
    int ir = r0 - 2 + sr, ic = c0 - 2 + sc;
    la[i] = xelem(sr, sc, kg);
    if ((unsigned)ir < 64u && (unsigned)ic < 64u) {
      int n = b * 4096 + ir * 64 + ic;
      v[i] = *(const bf16x8*)(featB + (size_t)n * KPAD + cs * 64 + kg * 8);
    } else {
      v[i] = (bf16x8){0, 0, 0, 0, 0, 0, 0, 0};
    }
  }
#pragma unroll
  for (int i = 0; i < 5; ++i)
    *(bf16x8*)&xt[la[i]] = v[i];
  __syncthreads();

  int i15 = lane & 15;
  int tq = lane >> 4;

  bf16x8 afr[2];
#pragma unroll
  for (int ks = 0; ks < 2; ++ks)
    afr[ks] = *(const bf16x8*)&xt[xelem(w + 2, 2 + i15, ks * 4 + tq)];

  int bBase[2][2];
#pragma unroll
  for (int bi = 0; bi < 2; ++bi)
#pragma unroll
    for (int ks = 0; ks < 2; ++ks)
      bBase[bi][ks] = xelem(w, bi * 4 + i15, ks * 4 + tq);

  int nb = b * 4096 + (r0 + w) * 64 + c0;
  bool take[2][4];
#pragma unroll
  for (int bi = 0; bi < 2; ++bi)
#pragma unroll
    for (int qq = 0; qq < 4; ++qq) {
      int r = 4 * tq + qq;
      int djp = bi * 4 + i15 - r;
      take[bi][qq] = (djp >= 0) && (djp <= 4) && (bi == 0 ? (r <= 7) : (r >= 8));
    }

#pragma unroll 1
  for (int di = 0; di < 5; ++di) {
    unsigned short* pb2 = part + (size_t)(cs * 5 + di) * NPIX * 5 + (size_t)5 * nb;
#pragma unroll
    for (int bi = 0; bi < 2; ++bi) {
      f32x4 acc = (f32x4){0.f, 0.f, 0.f, 0.f};
#pragma unroll
      for (int ks = 0; ks < 2; ++ks) {
        bf16x8 bfr = *(const bf16x8*)&xt[bBase[bi][ks] + di * 1280];
        acc = __builtin_amdgcn_mfma_f32_16x16x32_bf16(afr[ks], bfr, acc, 0, 0, 0);
      }
#pragma unroll
      for (int qq = 0; qq < 4; ++qq)
        if (take[bi][qq])
          pb2[4 * bi + 4 * qq + lane] = f2bf(acc[qq]);
    }
  }
}

// ---------- reduce partials, L2-normalize (4-lane split); zero-fill k 544..575 ----------
__global__ __launch_bounds__(256) void k_norm(const unsigned short* __restrict__ part,
                                              unsigned short* __restrict__ featB) {
  int t = blockIdx.x * 256 + threadIdx.x;   // 1024 blocks x 256
  int n = t >> 2, csh = t & 3;
  float g[25];
#pragma unroll
  for (int k = 0; k < 25; ++k) g[k] = 0.f;
#pragma unroll
  for (int cc = 0; cc < 2; ++cc) {
    int cs = csh * 2 + cc;
#pragma unroll
    for (int di = 0; di < 5; ++di) {
      const unsigned short* pp = part + ((size_t)(cs * 5 + di) * NPIX + n) * 5;
#pragma unroll
      for (int dj = 0; dj < 5; ++dj)
        g[di * 5 + dj] += bf2f(pp[dj]);
    }
  }
#pragma unroll
  for (int k = 0; k < 25; ++k) {
    g[k] += __shfl_xor(g[k], 1);
    g[k] += __shfl_xor(g[k], 2);
  }
  float ss = 0.f;
#pragma unroll
  for (int k = 0; k < 25; ++k) ss += g[k] * g[k];
  float inv = 1.0f / sqrtf(ss + 1e-6f);
  unsigned short buf[16];
#pragma unroll
  for (int j = 0; j < 16; ++j) {
    int k = csh * 16 + j;               // csh covers 512..575 (16 each)
    buf[j] = (k < 25) ? f2bf(g[k] * inv) : 0;
  }
  unsigned short* fb = featB + (size_t)n * KPAD + 512 + csh * 16;
  *(bf16x8*)(fb) = *(bf16x8*)&buf[0];
  *(bf16x8*)(fb + 8) = *(bf16x8*)&buf[8];
}

// ---------- GEMM: 256x256 tile, BK=64, 8 waves, st_16x32 swizzle, 2-deep vmcnt ----------
typedef __attribute__((address_space(3))) unsigned int as3_uint;
typedef const __attribute__((address_space(1))) unsigned int as1_uint;

__device__ __forceinline__ void glds16(const void* g, void* l) {
  __builtin_amdgcn_global_load_lds((as1_uint*)g, (as3_uint*)l, 16, 0, 0);
}

__global__ __launch_bounds__(512, 2) void k_gemm(const unsigned short* __restrict__ Wb,
                                                 const unsigned short* __restrict__ featB,
                                                 const float* __restrict__ bias,
                                                 float* __restrict__ out) {
  __shared__ __attribute__((aligned(16))) unsigned short As[2][16384]; // 2 x 32 KB
  __shared__ __attribute__((aligned(16))) unsigned short Bs[2][16384]; // 2 x 32 KB
  int g = blockIdx.x;
  int bid = (g & 7) * 64 + (g >> 3);    // XCD swizzle (512 = 8*64); mt-pair adjacent
  int mt = bid & 1;
  int nt = bid >> 1;
  int m0 = mt * 256;
  int n0 = nt * 256;
  int tid = threadIdx.x;
  int wave = tid >> 6;                  // 0..7 = 2m x 4n
  int lane = tid & 63;
  int wm = wave >> 2;                   // 0..1 -> rows wm*128..+128
  int wn = wave & 3;                    // 0..3 -> cols wn*64..+64

  // staging source coords from linear LDS slot (inverse st_16x32)
  int srow[4], scol[4];
#pragma unroll
  for (int i = 0; i < 4; ++i) {
    uint32_t L = (uint32_t)(i * 512 + tid) * 16;
    uint32_t Lp = L ^ (((L >> 9) & 1) << 5);
    srow[i] = Lp >> 7;                  // 0..255
    scol[i] = (Lp >> 4) & 7;            // 16B chunk within 128B row
  }

  auto STAGE = [&](int buf, int k0) {
#pragma unroll
    for (int i = 0; i < 4; ++i) {
      char* la = (char*)&As[buf][0] + i * 8192 + wave * 1024;
      char* lb = (char*)&Bs[buf][0] + i * 8192 + wave * 1024;
      glds16(Wb + (size_t)(m0 + srow[i]) * KPAD + k0 + scol[i] * 8, la);
      glds16(featB + (size_t)(n0 + srow[i]) * KPAD + k0 + scol[i] * 8, lb);
    }
  };

  int laneRow = lane & 15;
  int kswz[2];
#pragma unroll
  for (int ks = 0; ks < 2; ++ks)
    kswz[ks] = (ks * 64 + (lane >> 4) * 16) ^ ((lane & 4) << 3);

  f32x4 acc[8][4];
#pragma unroll
  for (int r = 0; r < 8; ++r)
#pragma unroll
    for (int c = 0; c < 4; ++c)
      acc[r][c] = (f32x4){0.f, 0.f, 0.f, 0.f};

  STAGE(0, 0);
  STAGE(1, 64);
  const int NT = 9;                     // K = 576 = 9 x 64
#pragma unroll 1
  for (int t = 0; t < NT; ++t) {
    if (t < NT - 1)
      asm volatile("s_waitcnt vmcnt(8)" ::: "memory");  // tile t landed; t+1 in flight
    else
      asm volatile("s_waitcnt vmcnt(0)" ::: "memory");  // tail drain
    __builtin_amdgcn_s_barrier();
    const char* Ab = (const char*)&As[t & 1][0];
    const char* Bb = (const char*)&Bs[t & 1][0];
#pragma unroll
    for (int mh = 0; mh < 2; ++mh) {
      bf16x8 af[4][2];
#pragma unroll
      for (int f = 0; f < 4; ++f)
#pragma unroll
        for (int ks = 0; ks < 2; ++ks)
          af[f][ks] = *(const bf16x8*)(Ab +
              (wm * 128 + mh * 64 + f * 16 + laneRow) * 128 + kswz[ks]);
#pragma unroll
      for (int nh = 0; nh < 2; ++nh) {
        bf16x8 bf[2][2];
#pragma unroll
        for (int nf = 0; nf < 2; ++nf)
#pragma unroll
          for (int ks = 0; ks < 2; ++ks)
            bf[nf][ks] = *(const bf16x8*)(Bb +
                (wn * 64 + nh * 32 + nf * 16 + laneRow) * 128 + kswz[ks]);
        __builtin_amdgcn_s_setprio(1);
#pragma unroll
        for (int f = 0; f < 4; ++f)
#pragma unroll
          for (int nf = 0; nf < 2; ++nf)
#pragma unroll
            for (int ks = 0; ks < 2; ++ks)
              acc[mh * 4 + f][nh * 2 + nf] = __builtin_amdgcn_mfma_f32_16x16x32_bf16(
                  af[f][ks], bf[nf][ks], acc[mh * 4 + f][nh * 2 + nf], 0, 0, 0);
        __builtin_amdgcn_s_setprio(0);
      }
    }
    __builtin_amdgcn_s_barrier();       // all reads of buf[t&1] done
    if (t + 2 < NT) STAGE(t & 1, (t + 2) * 64);
  }

  int bb = n0 >> 12;
  int hwb = n0 & 4095;
  float* outb = out + (size_t)bb * (HID * HW) + hwb;
#pragma unroll
  for (int f8 = 0; f8 < 8; ++f8) {
    int row0 = m0 + wm * 128 + f8 * 16 + (lane >> 4) * 4;
    float bv[4];
#pragma unroll
    for (int j = 0; j < 4; ++j) bv[j] = bias[row0 + j];
#pragma unroll
    for (int c = 0; c < 4; ++c) {
      int col = wn * 64 + (c >> 1) * 32 + (c & 1) * 16 + (lane & 15);
#pragma unroll
      for (int j = 0; j < 4; ++j) {
        float v2 = acc[f8][c][j] + bv[j];
        v2 = fmaxf(v2, 0.f);
        outb[(size_t)(row0 + j) * HW + col] = v2;
      }
    }
  }
}

extern "C" void kernel_launch(void* const* d_in, const int* in_sizes, int n_in,
                              void* d_out, int out_size, void* d_ws, size_t ws_size,
                              hipStream_t stream) {
  const float* x = (const float*)d_in[0];
  const float* W = (const float*)d_in[1];
  const float* bias = (const float*)d_in[2];
  float* out = (float*)d_out;
  char* ws = (char*)d_ws;
  // ws: featB 65536x576 bf16 = 75,497,472; Wb 512x576 bf16 = 589,824;
  //     part 40 x (65536*5) bf16 = 26,214,400  (total ~102.3 MB)
  unsigned short* featB = (unsigned short*)ws;
  unsigned short* Wb = (unsigned short*)(ws + 75497472);
  unsigned short* part = (unsigned short*)(ws + 76087296);

  k_prep<<<9344, 256, 0, stream>>>(x, featB, W, Wb);
  k_corr<<<8192, 256, 0, stream>>>(featB, part);
  k_norm<<<1024, 256, 0, stream>>>(part, featB);
  k_gemm<<<512, 512, 0, stream>>>(Wb, featB, bias, out);
}

// Round 22
// 138.342 us; speedup vs baseline: 1.0663x; 1.0030x over previous
//
#include <hip/hip_runtime.h>
#include <hip/hip_bf16.h>
#include <stdint.h>

#define C_IN 512
#define HW 4096
#define NPIX 65536
#define KPAD 576
#define KIN 537
#define HID 512

typedef __attribute__((ext_vector_type(8))) short bf16x8;
typedef __attribute__((ext_vector_type(4))) float f32x4;

__device__ __forceinline__ unsigned short f2bf(float f) {
  union { __hip_bfloat16 h; unsigned short u; } v;
  v.h = __float2bfloat16(f);
  return v.u;
}
__device__ __forceinline__ float bf2f(unsigned short h) {
  union { uint32_t u; float f; } v; v.u = ((uint32_t)h) << 16;
  return v.f;
}

// ---------- merged: x fp32 [c][n] -> featB bf16 [n][c]  AND  W -> Wb ----------
// Round-22 change (isolated): float2 loads along n (2 px/thread, 8 B/lane)
// halve the global-load instruction count at identical HBM traffic (dword-
// per-lane saturates VMEM issue ~5 TB/s; float2 tracks the 6.3 TB/s ceiling).
// Tile 128 px x 64 ch; LDS [128][72] (144B rows keep b128 reads 16B-aligned);
// granule-XOR kg^(px&7) bounds write conflicts at 4-way on a tiny op count.
#define PPAD 72
__global__ __launch_bounds__(256, 8) void k_prep(const float* __restrict__ x,
                                                 unsigned short* __restrict__ featB,
                                                 const float* __restrict__ W,
                                                 unsigned short* __restrict__ Wb) {
  __shared__ unsigned short sm[128 * PPAD];   // 18,432 B -> 8 blocks/CU
  int g = blockIdx.x;
  int t = threadIdx.x;
  if (g >= 4096) {                      // ---- W conversion tail (512 x 576, zero-pad)
    int idx = (g - 4096) * 256 + t;
    if (idx < HID * KPAD) {
      int o = idx / KPAD;
      int k = idx - o * KPAD;
      float v = (k < KIN) ? W[o * KIN + k] : 0.f;
      Wb[idx] = f2bf(v);
    }
    return;
  }
  int b = g >> 8, cg = (g >> 5) & 7, pt = g & 31;
  int c0 = cg * 64, p0 = pt * 128;
  int lane = t & 63, w = t >> 6;
  const float* xb = x + ((size_t)b * C_IN + c0) * HW + p0;
  int px0 = lane * 2;
#pragma unroll
  for (int i = 0; i < 8; ++i) {
    int ch = w * 16 + i * 2;
    float2 a  = *(const float2*)&xb[(size_t)ch * HW + px0];        // px {px0,px0+1}, ch
    float2 bq = *(const float2*)&xb[(size_t)(ch + 1) * HW + px0];  // ch+1
    uint32_t pk0 = (uint32_t)f2bf(a.x) | ((uint32_t)f2bf(bq.x) << 16);
    uint32_t pk1 = (uint32_t)f2bf(a.y) | ((uint32_t)f2bf(bq.y) << 16);
    int kg = ch >> 3, e0 = ch & 7;
    *(uint32_t*)&sm[px0 * PPAD + ((kg ^ (px0 & 7)) * 8 + e0)] = pk0;
    *(uint32_t*)&sm[(px0 + 1) * PPAD + ((kg ^ ((px0 + 1) & 7)) * 8 + e0)] = pk1;
  }
  __syncthreads();
#pragma unroll
  for (int i = 0; i < 4; ++i) {
    int flat = t + i * 256;             // (px,kg): 128 px x 8 kg
    int kg = flat & 7, px = flat >> 3;
    int n = b * 4096 + p0 + px;
    *(bf16x8*)(featB + (size_t)n * KPAD + c0 + kg * 8) =
        *(const bf16x8*)&sm[px * PPAD + ((kg ^ (px & 7)) * 8)];
  }
}

// ---------- MFMA correlation: band-harvest, XOR-64 LDS (round 18, stride 576) ----------
__device__ __forceinline__ int xelem(int sr, int sc, int kg) {
  return (sr * 20 + sc) * 64 + ((kg ^ (sc & 7)) * 8);
}

__global__ __launch_bounds__(256, 8) void k_corr(const unsigned short* __restrict__ featB,
                                                 unsigned short* __restrict__ part) {
  __shared__ unsigned short xt[8 * 20 * 64];  // 20,480 B
  int g = blockIdx.x;
  int bid = (g & 7) * 1024 + (g >> 3);  // bijective XCD swizzle (grid = 8*1024)
  int cs = bid & 7;
  int cg = (bid >> 3) & 3;
  int rg = (bid >> 5) & 15;
  int b  = bid >> 9;
  int t = threadIdx.x;
  int lane = t & 63;
  int w = t >> 6;
  int r0 = rg * 4, c0 = cg * 16;

  bf16x8 v[5];
  int la[5];
#pragma unroll
  for (int i = 0; i < 5; ++i) {
    int flat = t + i * 256;
    int kg = flat & 7, pxi = flat >> 3;
    int sc = pxi % 20, sr = pxi / 20;
    int ir = r0 - 2 + sr, ic = c0 - 2 + sc;
    la[i] = xelem(sr, sc, kg);
    if ((unsigned)ir < 64u && (unsigned)ic < 64u) {
      int n = b * 4096 + ir * 64 + ic;
      v[i] = *(const bf16x8*)(featB + (size_t)n * KPAD + cs * 64 + kg * 8);
    } else {
      v[i] = (bf16x8){0, 0, 0, 0, 0, 0, 0, 0};
    }
  }
#pragma unroll
  for (int i = 0; i < 5; ++i)
    *(bf16x8*)&xt[la[i]] = v[i];
  __syncthreads();

  int i15 = lane & 15;
  int tq = lane >> 4;

  bf16x8 afr[2];
#pragma unroll
  for (int ks = 0; ks < 2; ++ks)
    afr[ks] = *(const bf16x8*)&xt[xelem(w + 2, 2 + i15, ks * 4 + tq)];

  int bBase[2][2];
#pragma unroll
  for (int bi = 0; bi < 2; ++bi)
#pragma unroll
    for (int ks = 0; ks < 2; ++ks)
      bBase[bi][ks] = xelem(w, bi * 4 + i15, ks * 4 + tq);

  int nb = b * 4096 + (r0 + w) * 64 + c0;
  bool take[2][4];
#pragma unroll
  for (int bi = 0; bi < 2; ++bi)
#pragma unroll
    for (int qq = 0; qq < 4; ++qq) {
      int r = 4 * tq + qq;
      int djp = bi * 4 + i15 - r;
      take[bi][qq] = (djp >= 0) && (djp <= 4) && (bi == 0 ? (r <= 7) : (r >= 8));
    }

#pragma unroll 1
  for (int di = 0; di < 5; ++di) {
    unsigned short* pb2 = part + (size_t)(cs * 5 + di) * NPIX * 5 + (size_t)5 * nb;
#pragma unroll
    for (int bi = 0; bi < 2; ++bi) {
      f32x4 acc = (f32x4){0.f, 0.f, 0.f, 0.f};
#pragma unroll
      for (int ks = 0; ks < 2; ++ks) {
        bf16x8 bfr = *(const bf16x8*)&xt[bBase[bi][ks] + di * 1280];
        acc = __builtin_amdgcn_mfma_f32_16x16x32_bf16(afr[ks], bfr, acc, 0, 0, 0);
      }
#pragma unroll
      for (int qq = 0; qq < 4; ++qq)
        if (take[bi][qq])
          pb2[4 * bi + 4 * qq + lane] = f2bf(acc[qq]);
    }
  }
}

// ---------- reduce partials, L2-normalize (4-lane split); zero-fill k 544..575 ----------
__global__ __launch_bounds__(256) void k_norm(const unsigned short* __restrict__ part,
                                              unsigned short* __restrict__ featB) {
  int t = blockIdx.x * 256 + threadIdx.x;   // 1024 blocks x 256
  int n = t >> 2, csh = t & 3;
  float g[25];
#pragma unroll
  for (int k = 0; k < 25; ++k) g[k] = 0.f;
#pragma unroll
  for (int cc = 0; cc < 2; ++cc) {
    int cs = csh * 2 + cc;
#pragma unroll
    for (int di = 0; di < 5; ++di) {
      const unsigned short* pp = part + ((size_t)(cs * 5 + di) * NPIX + n) * 5;
#pragma unroll
      for (int dj = 0; dj < 5; ++dj)
        g[di * 5 + dj] += bf2f(pp[dj]);
    }
  }
#pragma unroll
  for (int k = 0; k < 25; ++k) {
    g[k] += __shfl_xor(g[k], 1);
    g[k] += __shfl_xor(g[k], 2);
  }
  float ss = 0.f;
#pragma unroll
  for (int k = 0; k < 25; ++k) ss += g[k] * g[k];
  float inv = 1.0f / sqrtf(ss + 1e-6f);
  unsigned short buf[16];
#pragma unroll
  for (int j = 0; j < 16; ++j) {
    int k = csh * 16 + j;               // csh covers 512..575 (16 each)
    buf[j] = (k < 25) ? f2bf(g[k] * inv) : 0;
  }
  unsigned short* fb = featB + (size_t)n * KPAD + 512 + csh * 16;
  *(bf16x8*)(fb) = *(bf16x8*)&buf[0];
  *(bf16x8*)(fb + 8) = *(bf16x8*)&buf[8];
}

// ---------- GEMM: 256x256 tile, BK=64, 8 waves, st_16x32 swizzle, 2-deep vmcnt ----------
typedef __attribute__((address_space(3))) unsigned int as3_uint;
typedef const __attribute__((address_space(1))) unsigned int as1_uint;

__device__ __forceinline__ void glds16(const void* g, void* l) {
  __builtin_amdgcn_global_load_lds((as1_uint*)g, (as3_uint*)l, 16, 0, 0);
}

__global__ __launch_bounds__(512, 2) void k_gemm(const unsigned short* __restrict__ Wb,
                                                 const unsigned short* __restrict__ featB,
                                                 const float* __restrict__ bias,
                                                 float* __restrict__ out) {
  __shared__ __attribute__((aligned(16))) unsigned short As[2][16384]; // 2 x 32 KB
  __shared__ __attribute__((aligned(16))) unsigned short Bs[2][16384]; // 2 x 32 KB
  int g = blockIdx.x;
  int bid = (g & 7) * 64 + (g >> 3);    // XCD swizzle (512 = 8*64); mt-pair adjacent
  int mt = bid & 1;
  int nt = bid >> 1;
  int m0 = mt * 256;
  int n0 = nt * 256;
  int tid = threadIdx.x;
  int wave = tid >> 6;                  // 0..7 = 2m x 4n
  int lane = tid & 63;
  int wm = wave >> 2;                   // 0..1 -> rows wm*128..+128
  int wn = wave & 3;                    // 0..3 -> cols wn*64..+64

  // staging source coords from linear LDS slot (inverse st_16x32)
  int srow[4], scol[4];
#pragma unroll
  for (int i = 0; i < 4; ++i) {
    uint32_t L = (uint32_t)(i * 512 + tid) * 16;
    uint32_t Lp = L ^ (((L >> 9) & 1) << 5);
    srow[i] = Lp >> 7;                  // 0..255
    scol[i] = (Lp >> 4) & 7;            // 16B chunk within 128B row
  }

  auto STAGE = [&](int buf, int k0) {
#pragma unroll
    for (int i = 0; i < 4; ++i) {
      char* la = (char*)&As[buf][0] + i * 8192 + wave * 1024;
      char* lb = (char*)&Bs[buf][0] + i * 8192 + wave * 1024;
      glds16(Wb + (size_t)(m0 + srow[i]) * KPAD + k0 + scol[i] * 8, la);
      glds16(featB + (size_t)(n0 + srow[i]) * KPAD + k0 + scol[i] * 8, lb);
    }
  };

  int laneRow = lane & 15;
  int kswz[2];
#pragma unroll
  for (int ks = 0; ks < 2; ++ks)
    kswz[ks] = (ks * 64 + (lane >> 4) * 16) ^ ((lane & 4) << 3);

  f32x4 acc[8][4];
#pragma unroll
  for (int r = 0; r < 8; ++r)
#pragma unroll
    for (int c = 0; c < 4; ++c)
      acc[r][c] = (f32x4){0.f, 0.f, 0.f, 0.f};

  STAGE(0, 0);
  STAGE(1, 64);
  const int NT = 9;                     // K = 576 = 9 x 64
#pragma unroll 1
  for (int t = 0; t < NT; ++t) {
    if (t < NT - 1)
      asm volatile("s_waitcnt vmcnt(8)" ::: "memory");  // tile t landed; t+1 in flight
    else
      asm volatile("s_waitcnt vmcnt(0)" ::: "memory");  // tail drain
    __builtin_amdgcn_s_barrier();
    const char* Ab = (const char*)&As[t & 1][0];
    const char* Bb = (const char*)&Bs[t & 1][0];
#pragma unroll
    for (int mh = 0; mh < 2; ++mh) {
      bf16x8 af[4][2];
#pragma unroll
      for (int f = 0; f < 4; ++f)
#pragma unroll
        for (int ks = 0; ks < 2; ++ks)
          af[f][ks] = *(const bf16x8*)(Ab +
              (wm * 128 + mh * 64 + f * 16 + laneRow) * 128 + kswz[ks]);
#pragma unroll
      for (int nh = 0; nh < 2; ++nh) {
        bf16x8 bf[2][2];
#pragma unroll
        for (int nf = 0; nf < 2; ++nf)
#pragma unroll
          for (int ks = 0; ks < 2; ++ks)
            bf[nf][ks] = *(const bf16x8*)(Bb +
                (wn * 64 + nh * 32 + nf * 16 + laneRow) * 128 + kswz[ks]);
        __builtin_amdgcn_s_setprio(1);
#pragma unroll
        for (int f = 0; f < 4; ++f)
#pragma unroll
          for (int nf = 0; nf < 2; ++nf)
#pragma unroll
            for (int ks = 0; ks < 2; ++ks)
              acc[mh * 4 + f][nh * 2 + nf] = __builtin_amdgcn_mfma_f32_16x16x32_bf16(
                  af[f][ks], bf[nf][ks], acc[mh * 4 + f][nh * 2 + nf], 0, 0, 0);
        __builtin_amdgcn_s_setprio(0);
      }
    }
    __builtin_amdgcn_s_barrier();       // all reads of buf[t&1] done
    if (t + 2 < NT) STAGE(t & 1, (t + 2) * 64);
  }

  int bb = n0 >> 12;
  int hwb = n0 & 4095;
  float* outb = out + (size_t)bb * (HID * HW) + hwb;
#pragma unroll
  for (int f8 = 0; f8 < 8; ++f8) {
    int row0 = m0 + wm * 128 + f8 * 16 + (lane >> 4) * 4;
    float bv[4];
#pragma unroll
    for (int j = 0; j < 4; ++j) bv[j] = bias[row0 + j];
#pragma unroll
    for (int c = 0; c < 4; ++c) {
      int col = wn * 64 + (c >> 1) * 32 + (c & 1) * 16 + (lane & 15);
#pragma unroll
      for (int j = 0; j < 4; ++j) {
        float v2 = acc[f8][c][j] + bv[j];
        v2 = fmaxf(v2, 0.f);
        outb[(size_t)(row0 + j) * HW + col] = v2;
      }
    }
  }
}

extern "C" void kernel_launch(void* const* d_in, const int* in_sizes, int n_in,
                              void* d_out, int out_size, void* d_ws, size_t ws_size,
                              hipStream_t stream) {
  const float* x = (const float*)d_in[0];
  const float* W = (const float*)d_in[1];
  const float* bias = (const float*)d_in[2];
  float* out = (float*)d_out;
  char* ws = (char*)d_ws;
  // ws: featB 65536x576 bf16 = 75,497,472; Wb 512x576 bf16 = 589,824;
  //     part 40 x (65536*5) bf16 = 26,214,400  (total ~102.3 MB)
  unsigned short* featB = (unsigned short*)ws;
  unsigned short* Wb = (unsigned short*)(ws + 75497472);
  unsigned short* part = (unsigned short*)(ws + 76087296);

  k_prep<<<5248, 256, 0, stream>>>(x, featB, W, Wb);
  k_corr<<<8192, 256, 0, stream>>>(featB, part);
  k_norm<<<1024, 256, 0, stream>>>(part, featB);
  k_gemm<<<512, 512, 0, stream>>>(Wb, featB, bias, out);
}